// Round 9
// baseline (296.339 us; speedup 1.0000x reference)
//
#include <hip/hip_runtime.h>

#define N_NODES 10000
#define E_EDGES 320000
#define F_IN    256
#define F_PROJ  200

#define EV_BYTES 400000000L         // 1e8 floats

#define PJ_BLOCKS 2500              // 4 nodes per block
#define A_BLOCKS  2048
#define A_CHUNK   40                // 2048*4 waves * 40 >= 320000
#define AGG_BLOCKS 160
#define AGG_N4    (N_NODES * F_IN / 4)      // 640000
#define AGG_PER_BLK (AGG_N4 / AGG_BLOCKS)   // 4000

// workspace layout (5.33 MB)
#define WS_P      0L           // 4,000,000  (bf16 P)
#define WS_EXP    4000000L     // 1,280,000  (expalpha)
#define WS_FLAGS  5280000L     // 40,000
#define WS_SUM    5320000L     // 16

__device__ __forceinline__ unsigned short f32_to_bf16(float f) {
    unsigned int u = __float_as_uint(f);
    u += 0x7FFFu + ((u >> 16) & 1u);
    return (unsigned short)(u >> 16);
}
__device__ __forceinline__ float bf16_to_f32(unsigned short b) {
    return __uint_as_float(((unsigned int)b) << 16);
}

// ---- K1: proj (4 nodes/block, 2500 blocks) + flag-scan ----------------------
__global__ __launch_bounds__(256) void k1_proj_flags(
        const float* __restrict__ x, const float* __restrict__ W,
        unsigned short* __restrict__ P, const int* __restrict__ ei,
        int* __restrict__ flags) {
    int bid = blockIdx.x, tid = threadIdx.x;
    int gt = bid * 256 + tid;                   // 640000 threads >= E
    if (gt < E_EDGES) flags[ei[E_EDGES + gt]] = 1;   // racy same-value: fine

    __shared__ float xs[4][F_IN];
    int n0 = bid * 4;
    // stage 4 rows of x (4 KB) with one float4 per thread
    ((float4*)xs)[tid] = ((const float4*)(x + (long)n0 * F_IN))[tid];
    __syncthreads();
    int j = tid;
    if (j >= F_PROJ) return;
    float acc[4] = {0.f, 0.f, 0.f, 0.f};
    for (int k = 0; k < F_IN; ++k) {
        float w = W[k * F_PROJ + j];
        #pragma unroll
        for (int r = 0; r < 4; ++r) acc[r] += xs[r][k] * w;
    }
    #pragma unroll
    for (int r = 0; r < 4; ++r) P[(long)(n0 + r) * F_PROJ + j] = f32_to_bf16(acc[r]);
}

// ---- K2: alpha (2048 blocks) ∥ agg (160 blocks) -----------------------------
__global__ __launch_bounds__(256) void k2_alpha_agg(
        const int* __restrict__ ei, const unsigned short* __restrict__ P,
        const float* __restrict__ Watt, const float* __restrict__ batt,
        float* __restrict__ expalpha, float* __restrict__ sumbuf,
        const int* __restrict__ flags, const float4* __restrict__ x4,
        float4* __restrict__ agg4) {
    int bid = blockIdx.x, tid = threadIdx.x;
    if (bid < A_BLOCKS) {
        __shared__ float bsum;
        if (tid == 0) bsum = 0.f;
        __syncthreads();
        int wid  = bid * 4 + (tid >> 6);
        int lane = tid & 63;
        float4 w4 = make_float4(0.f, 0.f, 0.f, 0.f);
        if (lane < 50) w4 = ((const float4*)Watt)[lane];
        float bias = batt[0];
        int e0 = wid * A_CHUNK;
        int e1 = min(e0 + A_CHUNK, E_EDGES);
        float lsum = 0.f;
        for (int e = e0; e < e1; ++e) {
            int s = ei[e];
            int d = ei[E_EDGES + e];
            float acc = 0.f;
            if (lane < 50) {
                uint2 us = *(const uint2*)(P + (long)s * F_PROJ + lane * 4);
                uint2 ud = *(const uint2*)(P + (long)d * F_PROJ + lane * 4);
                acc = fabsf(bf16_to_f32((unsigned short)(ud.x & 0xFFFF)) -
                            bf16_to_f32((unsigned short)(us.x & 0xFFFF))) * w4.x
                    + fabsf(bf16_to_f32((unsigned short)(ud.x >> 16)) -
                            bf16_to_f32((unsigned short)(us.x >> 16))) * w4.y
                    + fabsf(bf16_to_f32((unsigned short)(ud.y & 0xFFFF)) -
                            bf16_to_f32((unsigned short)(us.y & 0xFFFF))) * w4.z
                    + fabsf(bf16_to_f32((unsigned short)(ud.y >> 16)) -
                            bf16_to_f32((unsigned short)(us.y >> 16))) * w4.w;
            }
            #pragma unroll
            for (int off = 32; off; off >>= 1) acc += __shfl_down(acc, off);
            if (lane == 0) {
                float ea = expf(fmaxf(acc + bias, 0.f));   // alpha in [0,~6]
                expalpha[e] = ea;
                lsum += ea;
            }
        }
        if (lane == 0) atomicAdd(&bsum, lsum);
        __syncthreads();
        if (tid == 0) atomicAdd(sumbuf, bsum);
        return;
    }
    long base = (long)(bid - A_BLOCKS) * AGG_PER_BLK;
    for (int i = tid; i < AGG_PER_BLK; i += 256) {
        long i4 = base + i;
        float4 v = x4[i4];
        if (!flags[i4 >> 6]) v = make_float4(0.f, 0.f, 0.f, 0.f);
        agg4[i4] = v;
    }
}

// ---- K3: scatter a into ev (after the runtime d2d copy) ---------------------
__global__ __launch_bounds__(256) void k3_scatter(
        const int* __restrict__ ei, const float* __restrict__ expalpha,
        const float* __restrict__ sumbuf, float* __restrict__ ev) {
    int e = blockIdx.x * 256 + threadIdx.x;
    if (e >= E_EDGES) return;
    float a = expalpha[e] / sumbuf[0];
    int s = ei[e], d = ei[E_EDGES + e];
    ev[(long)s * N_NODES + d] = a;
    ev[(long)d * N_NODES + s] = a;
}

// ================= host ======================================================
extern "C" void kernel_launch(void* const* d_in, const int* in_sizes, int n_in,
                              void* d_out, int out_size, void* d_ws, size_t ws_size,
                              hipStream_t stream) {
    (void)in_sizes; (void)n_in; (void)out_size; (void)ws_size;
    const float* x         = (const float*)d_in[0];
    const float* edge_attr = (const float*)d_in[1];
    const int*   ei        = (const int*)d_in[2];
    const float* W_proj    = (const float*)d_in[3];
    // d_in[4] = b_proj: cancels in p_i - p_j, unused
    const float* W_att     = (const float*)d_in[5];
    const float* b_att     = (const float*)d_in[6];

    float* agg = (float*)d_out;
    float* ev  = (float*)d_out + (long)N_NODES * F_IN;
    char* ws = (char*)d_ws;

    unsigned short* P = (unsigned short*)(ws + WS_P);
    float* expalpha   = (float*)(ws + WS_EXP);
    int*   flags      = (int*)(ws + WS_FLAGS);
    float* sumbuf     = (float*)(ws + WS_SUM);

    hipMemsetAsync(ws + WS_FLAGS, 0, 40016, stream);

    // THE EXPERIMENT: runtime-tuned d2d bulk copy (blit/SDMA path) instead of
    // a hand-rolled copy kernel. Harness-blessed under graph capture.
    hipMemcpyAsync(ev, edge_attr, EV_BYTES, hipMemcpyDeviceToDevice, stream);

    k1_proj_flags<<<PJ_BLOCKS, 256, 0, stream>>>(x, W_proj, P, ei, flags);

    k2_alpha_agg<<<A_BLOCKS + AGG_BLOCKS, 256, 0, stream>>>(
        ei, P, W_att, b_att, expalpha, sumbuf, flags,
        (const float4*)x, (float4*)agg);

    k3_scatter<<<(E_EDGES + 255) / 256, 256, 0, stream>>>(
        ei, expalpha, sumbuf, ev);
}

// Round 10
// 253.254 us; speedup vs baseline: 1.1701x; 1.1701x over previous
//
#include <hip/hip_runtime.h>

#define N_NODES 10000
#define E_EDGES 320000
#define F_IN    256
#define F_PROJ  200

typedef float vfloat4 __attribute__((ext_vector_type(4)));

// ---- row-partitioned ev geometry (1 row = 10000 floats = 2500 float4) -------
#define ROW_F4      2500L
#define R1          2400            // K1 copies rows [0, R1)
#define R2          6200            // K2 copies rows [R1, R2); K3 copies [R2, N)
#define C1_F4_BEG   0L
#define C1_F4_END   (R1 * ROW_F4)                 //  6.0M f4
#define C2_F4_BEG   C1_F4_END
#define C2_F4_END   ((long)R2 * ROW_F4)           // 15.5M f4
#define C3_F4_BEG   C2_F4_END
#define C3_F4_END   (N_NODES * ROW_F4)            // 25.0M f4

#define PJ_BLOCKS   2500            // 4 nodes per block; 640k threads >= E
#define K1_COPY_BLOCKS 1024
#define A_BLOCKS    2048
#define A_CHUNK     40              // 2048*4 waves * 40 >= 320000
#define AGG_BLOCKS  160
#define AGG_N4      (N_NODES * F_IN / 4)     // 640000
#define AGG_PER_BLK (AGG_N4 / AGG_BLOCKS)    // 4000
#define K2_COPY_BLOCKS 2048
#define K3_COPY_BLOCKS 2048
#define SC_BLOCKS   1250            // E / 256

// workspace layout (5.33 MB)
#define WS_P      0L           // 4,000,000  (bf16 P)
#define WS_EXP    4000000L     // 1,280,000  (expalpha)
#define WS_FLAGS  5280000L     // 40,000
#define WS_SUM    5320000L     // 16

__device__ __forceinline__ unsigned short f32_to_bf16(float f) {
    unsigned int u = __float_as_uint(f);
    u += 0x7FFFu + ((u >> 16) & 1u);
    return (unsigned short)(u >> 16);
}
__device__ __forceinline__ float bf16_to_f32(unsigned short b) {
    return __uint_as_float(((unsigned int)b) << 16);
}

// nt grid-stride copy of f4 range [beg, end) over nblk*256 threads
__device__ __forceinline__ void nt_copy_range(
        const vfloat4* __restrict__ src, vfloat4* __restrict__ dst,
        long beg, long end, int cid, int nblk, int tid) {
    long i = beg + (long)cid * 256 + tid;
    const long stride = (long)nblk * 256;
    for (; i < end; i += stride) {
        vfloat4 v = __builtin_nontemporal_load(src + i);
        __builtin_nontemporal_store(v, dst + i);
    }
}

// ---- K1: proj (4 nodes/blk) + flag-scan  ∥  nt-copy rows [0, R1) ------------
__global__ __launch_bounds__(256) void k1_proj_flags_copy(
        const float* __restrict__ x, const float* __restrict__ W,
        unsigned short* __restrict__ P, const int* __restrict__ ei,
        int* __restrict__ flags,
        const vfloat4* __restrict__ csrc, vfloat4* __restrict__ cdst) {
    int bid = blockIdx.x, tid = threadIdx.x;
    if (bid >= PJ_BLOCKS) {
        nt_copy_range(csrc, cdst, C1_F4_BEG, C1_F4_END,
                      bid - PJ_BLOCKS, K1_COPY_BLOCKS, tid);
        return;
    }
    int gt = bid * 256 + tid;                        // 640000 threads
    if (gt < E_EDGES) flags[ei[E_EDGES + gt]] = 1;   // racy same-value: fine

    __shared__ float xs[4][F_IN];
    int n0 = bid * 4;
    ((float4*)xs)[tid] = ((const float4*)(x + (long)n0 * F_IN))[tid];
    __syncthreads();
    int j = tid;
    if (j >= F_PROJ) return;
    float acc[4] = {0.f, 0.f, 0.f, 0.f};
    for (int k = 0; k < F_IN; ++k) {
        float w = W[k * F_PROJ + j];
        #pragma unroll
        for (int r = 0; r < 4; ++r) acc[r] += xs[r][k] * w;
    }
    #pragma unroll
    for (int r = 0; r < 4; ++r) P[(long)(n0 + r) * F_PROJ + j] = f32_to_bf16(acc[r]);
}

// ---- K2: alpha (2048) ∥ agg (160) ∥ nt-copy rows [R1, R2) (2048) ------------
__global__ __launch_bounds__(256) void k2_alpha_agg_copy(
        const int* __restrict__ ei, const unsigned short* __restrict__ P,
        const float* __restrict__ Watt, const float* __restrict__ batt,
        float* __restrict__ expalpha, float* __restrict__ sumbuf,
        const int* __restrict__ flags, const float4* __restrict__ x4,
        float4* __restrict__ agg4,
        const vfloat4* __restrict__ csrc, vfloat4* __restrict__ cdst) {
    int bid = blockIdx.x, tid = threadIdx.x;
    if (bid < A_BLOCKS) {
        __shared__ float bsum;
        if (tid == 0) bsum = 0.f;
        __syncthreads();
        int wid  = bid * 4 + (tid >> 6);
        int lane = tid & 63;
        float4 w4 = make_float4(0.f, 0.f, 0.f, 0.f);
        if (lane < 50) w4 = ((const float4*)Watt)[lane];
        float bias = batt[0];
        int e0 = wid * A_CHUNK;
        int e1 = min(e0 + A_CHUNK, E_EDGES);
        float lsum = 0.f;
        for (int e = e0; e < e1; ++e) {
            int s = ei[e];
            int d = ei[E_EDGES + e];
            float acc = 0.f;
            if (lane < 50) {
                uint2 us = *(const uint2*)(P + (long)s * F_PROJ + lane * 4);
                uint2 ud = *(const uint2*)(P + (long)d * F_PROJ + lane * 4);
                acc = fabsf(bf16_to_f32((unsigned short)(ud.x & 0xFFFF)) -
                            bf16_to_f32((unsigned short)(us.x & 0xFFFF))) * w4.x
                    + fabsf(bf16_to_f32((unsigned short)(ud.x >> 16)) -
                            bf16_to_f32((unsigned short)(us.x >> 16))) * w4.y
                    + fabsf(bf16_to_f32((unsigned short)(ud.y & 0xFFFF)) -
                            bf16_to_f32((unsigned short)(us.y & 0xFFFF))) * w4.z
                    + fabsf(bf16_to_f32((unsigned short)(ud.y >> 16)) -
                            bf16_to_f32((unsigned short)(us.y >> 16))) * w4.w;
            }
            #pragma unroll
            for (int off = 32; off; off >>= 1) acc += __shfl_down(acc, off);
            if (lane == 0) {
                float ea = expf(fmaxf(acc + bias, 0.f));   // alpha in [0,~6]
                expalpha[e] = ea;
                lsum += ea;
            }
        }
        if (lane == 0) atomicAdd(&bsum, lsum);
        __syncthreads();
        if (tid == 0) atomicAdd(sumbuf, bsum);
        return;
    }
    int b2 = bid - A_BLOCKS;
    if (b2 < AGG_BLOCKS) {
        long base = (long)b2 * AGG_PER_BLK;
        for (int i = tid; i < AGG_PER_BLK; i += 256) {
            long i4 = base + i;
            float4 v = x4[i4];
            if (!flags[i4 >> 6]) v = make_float4(0.f, 0.f, 0.f, 0.f);
            agg4[i4] = v;
        }
        return;
    }
    nt_copy_range(csrc, cdst, C2_F4_BEG, C2_F4_END,
                  b2 - AGG_BLOCKS, K2_COPY_BLOCKS, tid);
}

// ---- K3: nt-copy rows [R2, N) (2048) ∥ scatter cells with row < R2 (1250) ---
// Copy region and scatter rows are DISJOINT; scatter rows were completed by
// K1/K2 (kernel-boundary ordering) => race-free, scatter hidden under copy.
__global__ __launch_bounds__(256) void k3_copy_scatter_lo(
        const int* __restrict__ ei, const float* __restrict__ expalpha,
        const float* __restrict__ sumbuf, float* __restrict__ ev,
        const vfloat4* __restrict__ csrc, vfloat4* __restrict__ cdst) {
    int bid = blockIdx.x, tid = threadIdx.x;
    if (bid < K3_COPY_BLOCKS) {
        nt_copy_range(csrc, cdst, C3_F4_BEG, C3_F4_END, bid, K3_COPY_BLOCKS, tid);
        return;
    }
    int e = (bid - K3_COPY_BLOCKS) * 256 + tid;
    if (e >= E_EDGES) return;
    float a = expalpha[e] / sumbuf[0];
    int s = ei[e], d = ei[E_EDGES + e];
    if (s < R2) ev[(long)s * N_NODES + d] = a;
    if (d < R2) ev[(long)d * N_NODES + s] = a;
}

// ---- K4: scatter cells with row >= R2 (rows copied in K3) -------------------
__global__ __launch_bounds__(256) void k4_scatter_hi(
        const int* __restrict__ ei, const float* __restrict__ expalpha,
        const float* __restrict__ sumbuf, float* __restrict__ ev) {
    int e = blockIdx.x * 256 + threadIdx.x;
    if (e >= E_EDGES) return;
    float a = expalpha[e] / sumbuf[0];
    int s = ei[e], d = ei[E_EDGES + e];
    if (s >= R2) ev[(long)s * N_NODES + d] = a;
    if (d >= R2) ev[(long)d * N_NODES + s] = a;
}

// ================= host ======================================================
extern "C" void kernel_launch(void* const* d_in, const int* in_sizes, int n_in,
                              void* d_out, int out_size, void* d_ws, size_t ws_size,
                              hipStream_t stream) {
    (void)in_sizes; (void)n_in; (void)out_size; (void)ws_size;
    const float* x         = (const float*)d_in[0];
    const float* edge_attr = (const float*)d_in[1];
    const int*   ei        = (const int*)d_in[2];
    const float* W_proj    = (const float*)d_in[3];
    // d_in[4] = b_proj: cancels in p_i - p_j, unused
    const float* W_att     = (const float*)d_in[5];
    const float* b_att     = (const float*)d_in[6];

    float* agg = (float*)d_out;
    float* ev  = (float*)d_out + (long)N_NODES * F_IN;
    char* ws = (char*)d_ws;

    unsigned short* P = (unsigned short*)(ws + WS_P);
    float* expalpha   = (float*)(ws + WS_EXP);
    int*   flags      = (int*)(ws + WS_FLAGS);
    float* sumbuf     = (float*)(ws + WS_SUM);

    hipMemsetAsync(ws + WS_FLAGS, 0, 40016, stream);

    k1_proj_flags_copy<<<PJ_BLOCKS + K1_COPY_BLOCKS, 256, 0, stream>>>(
        x, W_proj, P, ei, flags, (const vfloat4*)edge_attr, (vfloat4*)ev);

    k2_alpha_agg_copy<<<A_BLOCKS + AGG_BLOCKS + K2_COPY_BLOCKS, 256, 0, stream>>>(
        ei, P, W_att, b_att, expalpha, sumbuf, flags,
        (const float4*)x, (float4*)agg,
        (const vfloat4*)edge_attr, (vfloat4*)ev);

    k3_copy_scatter_lo<<<K3_COPY_BLOCKS + SC_BLOCKS, 256, 0, stream>>>(
        ei, expalpha, sumbuf, ev, (const vfloat4*)edge_attr, (vfloat4*)ev);

    k4_scatter_hi<<<SC_BLOCKS, 256, 0, stream>>>(ei, expalpha, sumbuf, ev);
}